// Round 4
// baseline (702.402 us; speedup 1.0000x reference)
//
#include <hip/hip_runtime.h>
#include <hip/hip_bf16.h>
#include <math.h>

typedef __hip_bfloat16 bf16;
typedef __attribute__((ext_vector_type(8))) short s8v;   // 8 bf16 bit-carrier (4 VGPR)
typedef __attribute__((ext_vector_type(4))) float f4v;   // MFMA 16x16 accumulator

#define Bn  32
#define Cn  160
#define HWn 3136
#define Pn  100352

__device__ __forceinline__ float b2f(bf16 v){ return __bfloat162float(v); }
__device__ __forceinline__ bf16  f2b(float v){ return __float2bfloat16(v); }
__device__ __forceinline__ float bits2f(unsigned short u){
    union { float f; unsigned int i; } x; x.i = ((unsigned int)u) << 16; return x.f;
}
__device__ __forceinline__ float gelu_f(float x){ return 0.5f*x*(1.0f + erff(x*0.7071067811865476f)); }

#define MFMA(a,b,c) __builtin_amdgcn_mfma_f32_16x16x32_bf16((a),(b),(c),0,0,0)

// ---------------- K0: weight prep (fp32 -> bf16, concat/pad) ----------------
__global__ __launch_bounds__(256) void k0_prep(
    const float* __restrict__ wt, const float* __restrict__ wb_, const float* __restrict__ wr,
    const float* __restrict__ wl, const float* __restrict__ wc,
    const float* __restrict__ bt, const float* __restrict__ bb_, const float* __restrict__ br,
    const float* __restrict__ bl, const float* __restrict__ bc,
    const float* __restrict__ wf1, const float* __restrict__ bf1,
    const float* __restrict__ g2, const float* __restrict__ b2, const float* __restrict__ m2, const float* __restrict__ v2,
    const float* __restrict__ wf2, const float* __restrict__ wfc1, const float* __restrict__ wfc2,
    const float* __restrict__ wph, const float* __restrict__ wpw,
    bf16* wcat, bf16* wf1b, bf16* wf2b, bf16* wfc1b, bf16* wfc2b, bf16* wphb, bf16* wpwb,
    float* bcat, float* epsv, float* eptv)
{
    int idx = blockIdx.x*256 + threadIdx.x;
    if (idx < 25600){ int o = idx/160, k = idx - o*160; int gi = o>>5, oo = o&31;
        const float* wp = gi==0?wt: gi==1?wb_: gi==2?wr: gi==3?wl: wc;
        wcat[idx] = f2b(wp[oo*160+k]); return; }
    idx -= 25600;
    if (idx < 25600){ wf1b[idx] = f2b(wf1[idx]); return; }
    idx -= 25600;
    if (idx < 76800){ wf2b[idx] = f2b(wf2[idx]); return; }
    idx -= 76800;
    if (idx < 76800){ wfc1b[idx] = f2b(wfc1[idx]); return; }
    idx -= 76800;
    if (idx < 76800){ wfc2b[idx] = f2b(wfc2[idx]); return; }
    idx -= 76800;
    if (idx < 4096){ int v = idx>>6, w = idx&63;
        wphb[idx] = (v<56 && w<56) ? f2b(wph[v*56+w]) : f2b(0.f); return; }
    idx -= 4096;
    if (idx < 4096){ int v = idx>>6, w = idx&63;
        wpwb[idx] = (v<56 && w<56) ? f2b(wpw[v*56+w]) : f2b(0.f); return; }
    idx -= 4096;
    if (idx < 160){ int o = idx; int gi = o>>5, oo = o&31;
        const float* bp = gi==0?bt: gi==1?bb_: gi==2?br: gi==3?bl: bc;
        bcat[o] = bp[oo]; return; }
    idx -= 160;
    if (idx < 160){ int o = idx; float s = g2[o]*rsqrtf(v2[o]+1e-5f);
        epsv[o] = s; eptv[o] = (bf1[o]-m2[o])*s + b2[o]; return; }
}

// ---------------- K1: x (NCHW fp32) -> hT = gelu(bn1(x)) (BHWC bf16) ----------------
__global__ __launch_bounds__(256) void k1_bn_gelu_tr(const float* __restrict__ x,
    const float* __restrict__ g, const float* __restrict__ b,
    const float* __restrict__ m, const float* __restrict__ v,
    bf16* __restrict__ hT)
{
    __shared__ float tile[64*161];
    __shared__ float sc[160], sh[160];
    int blk = blockIdx.x; int bb = blk/49; int hw0 = (blk - bb*49)*64;
    int tid = threadIdx.x;
    if (tid < 160){
        float s = g[tid] * rsqrtf(v[tid] + 1e-5f);
        sc[tid] = s; sh[tid] = b[tid] - m[tid]*s;
    }
    __syncthreads();
    const float* xb = x + (size_t)bb*Cn*HWn + hw0;
    for (int idx = tid; idx < 160*64; idx += 256){
        int c = idx >> 6, p = idx & 63;
        float val = xb[(size_t)c*HWn + p];
        tile[p*161 + c] = gelu_f(val*sc[c] + sh[c]);
    }
    __syncthreads();
    bf16* ho = hT + ((size_t)bb*HWn + hw0)*Cn;
    for (int idx = tid; idx < 64*160; idx += 256){
        int p = idx/160, c = idx - p*160;
        ho[idx] = f2b(tile[p*161 + c]);
    }
}

// ---------------- K2: conv5 GEMM — A regs from global, B regs from global (L2-hit) ----------------
__global__ __launch_bounds__(256) void k2_conv5(const bf16* __restrict__ hT,
    const bf16* __restrict__ wcat, const float* __restrict__ bcat, bf16* __restrict__ y5T)
{
    int tid = threadIdx.x, wave = tid>>6, lane = tid&63, m = lane&15, q = lane>>4;
    size_t pos0 = (size_t)blockIdx.x*64;
    const unsigned short* Ap = (const unsigned short*)hT + (pos0 + wave*16 + m)*160 + q*8;
    s8v a[5];
    #pragma unroll
    for (int kb = 0; kb < 5; ++kb) a[kb] = *(const s8v*)(Ap + kb*32);
    const unsigned short* wbase = (const unsigned short*)wcat + m*160 + q*8;
    for (int s = 0; s < 10; ++s){
        const unsigned short* Bp = wbase + s*16*160;
        f4v acc = {0.f,0.f,0.f,0.f};
        #pragma unroll
        for (int kb = 0; kb < 5; ++kb) acc = MFMA(a[kb], *(const s8v*)(Bp + kb*32), acc);
        float bias = bcat[s*16 + m];
        bf16* yo = y5T + (pos0 + wave*16 + q*4)*160 + s*16 + m;
        #pragma unroll
        for (int r = 0; r < 4; ++r) yo[r*160] = f2b(acc[r] + bias);
    }
}

// ---------------- K3: shifted-A GEMM + bn2 + gelu -> gT (B from global) ----------------
__global__ __launch_bounds__(256) void k3_wf1(const bf16* __restrict__ y5T,
    const bf16* __restrict__ wf1b, const float* __restrict__ epsv, const float* __restrict__ eptv,
    bf16* __restrict__ gT)
{
    int tid = threadIdx.x, wave = tid>>6, lane = tid&63, m = lane&15, q = lane>>4;
    int blk = blockIdx.x; int bb = blk/49; int hw0 = (blk - bb*49)*64;
    size_t pos0 = (size_t)bb*HWn + hw0;
    int phw = hw0 + wave*16 + m; int h = phw/56, w = phw - h*56;
    s8v a[5];
    #pragma unroll
    for (int kb = 0; kb < 5; ++kb){
        int h2 = h, w2 = w; bool ok = true;
        if      (kb == 0){ h2 = h+1; ok = (h2 < 56); }
        else if (kb == 1){ h2 = h-1; ok = (h2 >= 0); }
        else if (kb == 2){ w2 = w-1; ok = (w2 >= 0); }
        else if (kb == 3){ w2 = w+1; ok = (w2 < 56); }
        if (ok){
            const unsigned short* Ap = (const unsigned short*)y5T +
                ((size_t)bb*HWn + h2*56 + w2)*160 + kb*32 + q*8;
            a[kb] = *(const s8v*)Ap;
        } else {
            a[kb] = (s8v){0,0,0,0,0,0,0,0};
        }
    }
    const unsigned short* wbase = (const unsigned short*)wf1b + m*160 + q*8;
    for (int s = 0; s < 10; ++s){
        const unsigned short* Bp = wbase + s*16*160;
        f4v acc = {0.f,0.f,0.f,0.f};
        #pragma unroll
        for (int kb = 0; kb < 5; ++kb) acc = MFMA(a[kb], *(const s8v*)(Bp + kb*32), acc);
        int o = s*16 + m;
        float es = epsv[o], et = eptv[o];
        bf16* go = gT + (pos0 + wave*16 + q*4)*160 + o;
        #pragma unroll
        for (int r = 0; r < 4; ++r) go[r*160] = f2b(gelu_f(acc[r]*es + et));
    }
}

// ---------------- K4: proj_h MFMA ----------------
__global__ __launch_bounds__(256) void k4_projh(const bf16* __restrict__ gT,
    const bf16* __restrict__ wphb, const float* __restrict__ bph, bf16* __restrict__ xhT)
{
    __shared__ __align__(16) unsigned short gS[160*72];
    int tid = threadIdx.x, wave = tid>>6, lane = tid&63, m = lane&15, q = lane>>4;
    int blk = blockIdx.x; int b = blk/56, h = blk - b*56;
    const unsigned short* ga = (const unsigned short*)gT + ((size_t)b*HWn + h*56)*160;
    for (int idx = tid; idx < 56*160; idx += 256){
        int w = idx/160, c = idx - w*160;
        gS[c*72 + w] = ga[idx];
    }
    for (int idx = tid; idx < 160*8; idx += 256){
        int c = idx>>3, w = 56 + (idx&7);
        gS[c*72 + w] = 0;
    }
    __syncthreads();
    int v0 = wave*16;
    s8v a[2];
    #pragma unroll
    for (int kb = 0; kb < 2; ++kb)
        a[kb] = *(const s8v*)((const unsigned short*)wphb + (v0+m)*64 + kb*32 + q*8);
    int v = v0 + q*4;
    for (int s = 0; s < 10; ++s){
        f4v acc = {0.f,0.f,0.f,0.f};
        const unsigned short* Bp = &gS[(s*16+m)*72 + q*8];
        #pragma unroll
        for (int kb = 0; kb < 2; ++kb) acc = MFMA(a[kb], *(const s8v*)(Bp + kb*32), acc);
        #pragma unroll
        for (int r = 0; r < 4; ++r){
            int vv = v + r;
            if (vv < 56)
                xhT[((size_t)b*HWn + h*56 + vv)*160 + s*16 + m] = f2b(acc[r] + bph[vv]);
        }
    }
}

// ---------------- K5: proj_w MFMA ----------------
__global__ __launch_bounds__(256) void k5_projw(const bf16* __restrict__ gT,
    const bf16* __restrict__ wpwb, const float* __restrict__ bpw, bf16* __restrict__ xwT)
{
    __shared__ __align__(16) unsigned short gS[160*72];
    int tid = threadIdx.x, wave = tid>>6, lane = tid&63, m = lane&15, q = lane>>4;
    int blk = blockIdx.x; int b = blk/56, w = blk - b*56;
    const unsigned short* gbase = (const unsigned short*)gT + ((size_t)b*HWn + w)*160;
    for (int idx = tid; idx < 56*160; idx += 256){
        int hh = idx/160, c = idx - hh*160;
        gS[c*72 + hh] = gbase[(size_t)hh*56*160 + c];
    }
    for (int idx = tid; idx < 160*8; idx += 256){
        int c = idx>>3, hh = 56 + (idx&7);
        gS[c*72 + hh] = 0;
    }
    __syncthreads();
    int v0 = wave*16;
    s8v a[2];
    #pragma unroll
    for (int kb = 0; kb < 2; ++kb)
        a[kb] = *(const s8v*)((const unsigned short*)wpwb + (v0+m)*64 + kb*32 + q*8);
    int v = v0 + q*4;
    for (int s = 0; s < 10; ++s){
        f4v acc = {0.f,0.f,0.f,0.f};
        const unsigned short* Bp = &gS[(s*16+m)*72 + q*8];
        #pragma unroll
        for (int kb = 0; kb < 2; ++kb) acc = MFMA(a[kb], *(const s8v*)(Bp + kb*32), acc);
        #pragma unroll
        for (int r = 0; r < 4; ++r){
            int vv = v + r;
            if (vv < 56)
                xwT[((size_t)b*HWn + vv*56 + w)*160 + s*16 + m] = f2b(acc[r] + bpw[vv]);
        }
    }
}

// ---------------- K6: wf2 GEMM (K=480 concat) -> gm bf16 BHWC (B from global, no LDS) --------
__global__ __launch_bounds__(256) void k6_wf2(const bf16* __restrict__ gT,
    const bf16* __restrict__ xhT, const bf16* __restrict__ xwT,
    const bf16* __restrict__ wf2b, bf16* __restrict__ gm)
{
    int tid = threadIdx.x, wave = tid>>6, lane = tid&63, m = lane&15, q = lane>>4;
    size_t pos0 = (size_t)blockIdx.x*64;
    size_t prow = (pos0 + wave*16 + m)*160;
    s8v a[15];
    #pragma unroll
    for (int kb = 0; kb < 15; ++kb){
        const bf16* src = (kb < 5) ? gT : (kb < 10 ? xhT : xwT);
        int kc = (kb - (kb < 5 ? 0 : (kb < 10 ? 5 : 10)))*32 + q*8;
        a[kb] = *(const s8v*)((const unsigned short*)src + prow + kc);
    }
    const unsigned short* wbase = (const unsigned short*)wf2b + m*480 + q*8;
    for (int s = 0; s < 10; ++s){
        const unsigned short* Bp = wbase + s*16*480;
        f4v acc = {0.f,0.f,0.f,0.f};
        #pragma unroll
        for (int kb = 0; kb < 15; ++kb) acc = MFMA(a[kb], *(const s8v*)(Bp + kb*32), acc);
        bf16* go = gm + (pos0 + wave*16 + q*4)*160 + s*16 + m;
        #pragma unroll
        for (int r = 0; r < 4; ++r) go[r*160] = f2b(acc[r]);
    }
}

// ---------------- K7: LN(x+gm) + fc1 + gelu -> u [pos][480] bf16 (B from global, no strip barriers) ----
__global__ __launch_bounds__(256) void k7_ln_fc1(const float* __restrict__ x,
    const bf16* __restrict__ gm,
    const float* __restrict__ lng, const float* __restrict__ lnb,
    const bf16* __restrict__ wfc1b, const float* __restrict__ bfc1, bf16* __restrict__ u)
{
    __shared__ float Xs[64*161];
    __shared__ __align__(16) unsigned short As[64*168];
    int tid = threadIdx.x, wave = tid>>6, lane = tid&63, m = lane&15, q = lane>>4;
    int blk = blockIdx.x; int bb = blk/49; int hw0 = (blk - bb*49)*64;
    size_t pos0 = (size_t)bb*HWn + hw0;
    const float* xb = x + (size_t)bb*Cn*HWn + hw0;
    for (int idx = tid; idx < 160*64; idx += 256){
        int o = idx >> 6, p = idx & 63;
        Xs[p*161 + o] = xb[(size_t)o*HWn + p];
    }
    __syncthreads();
    {
        const unsigned short* gp = (const unsigned short*)gm + pos0*160;
        for (int idx = tid; idx < 64*160; idx += 256){
            int p = idx/160, c = idx - p*160;
            Xs[p*161 + c] += bits2f(gp[idx]);
        }
    }
    __syncthreads();
    {
        int p = tid >> 2, q4 = tid & 3;
        float vbuf[40];
        float s = 0.f, ss = 0.f;
        const float* row = &Xs[p*161 + q4*40];
        #pragma unroll
        for (int i = 0; i < 40; ++i){ float vv = row[i]; vbuf[i] = vv; s += vv; ss += vv*vv; }
        s  += __shfl_xor(s, 1);  ss += __shfl_xor(ss, 1);
        s  += __shfl_xor(s, 2);  ss += __shfl_xor(ss, 2);
        float mean = s * (1.f/160.f);
        float var  = ss * (1.f/160.f) - mean*mean;
        float rstd = rsqrtf(var + 1e-5f);
        unsigned short* arow = &As[p*168 + q4*40];
        #pragma unroll
        for (int i = 0; i < 40; ++i){
            int c = q4*40 + i;
            float nv = (vbuf[i] - mean)*rstd*lng[c] + lnb[c];
            union { unsigned short us; bf16 b; } cv; cv.b = f2b(nv);
            arow[i] = cv.us;
        }
    }
    __syncthreads();
    s8v a[5];
    const unsigned short* Ap = &As[(wave*16 + m)*168 + q*8];
    #pragma unroll
    for (int kb = 0; kb < 5; ++kb) a[kb] = *(const s8v*)(Ap + kb*32);
    const unsigned short* wbase = (const unsigned short*)wfc1b + m*160 + q*8;
    for (int s = 0; s < 30; ++s){
        const unsigned short* Bp = wbase + s*16*160;
        f4v acc = {0.f,0.f,0.f,0.f};
        #pragma unroll
        for (int kb = 0; kb < 5; ++kb) acc = MFMA(a[kb], *(const s8v*)(Bp + kb*32), acc);
        float bias = bfc1[s*16 + m];
        bf16* uo = u + (pos0 + wave*16 + q*4)*480 + s*16 + m;
        #pragma unroll
        for (int r = 0; r < 4; ++r) uo[r*480] = f2b(gelu_f(acc[r] + bias));
    }
}

// ---------------- K8: fc2 (K=480) + bfc2 + (x+gm) residual -> out NCHW fp32 ----------------
__global__ __launch_bounds__(256) void k8_fc2(const bf16* __restrict__ u,
    const bf16* __restrict__ wfc2b, const float* __restrict__ bfc2,
    const float* __restrict__ x, const bf16* __restrict__ gm, float* __restrict__ out)
{
    __shared__ float Ds[64*161];
    int tid = threadIdx.x, wave = tid>>6, lane = tid&63, m = lane&15, q = lane>>4;
    int blk = blockIdx.x; int bb = blk/49; int hw0 = (blk - bb*49)*64;
    size_t pos0 = (size_t)bb*HWn + hw0;
    const float* xb = x + (size_t)bb*Cn*HWn + hw0;
    for (int idx = tid; idx < 160*64; idx += 256){
        int o = idx >> 6, p = idx & 63;
        Ds[p*161 + o] = xb[(size_t)o*HWn + p];
    }
    __syncthreads();
    {
        const unsigned short* gp = (const unsigned short*)gm + pos0*160;
        for (int idx = tid; idx < 64*160; idx += 256){
            int p = idx/160, c = idx - p*160;
            Ds[p*161 + c] += bits2f(gp[idx]);
        }
    }
    __syncthreads();
    const unsigned short* Ap = (const unsigned short*)u + (pos0 + wave*16 + m)*480 + q*8;
    s8v a[15];
    #pragma unroll
    for (int kb = 0; kb < 15; ++kb) a[kb] = *(const s8v*)(Ap + kb*32);
    const unsigned short* wbase = (const unsigned short*)wfc2b + m*480 + q*8;
    for (int s = 0; s < 10; ++s){
        const unsigned short* Bp = wbase + s*16*480;
        f4v acc = {0.f,0.f,0.f,0.f};
        #pragma unroll
        for (int kb = 0; kb < 15; ++kb) acc = MFMA(a[kb], *(const s8v*)(Bp + kb*32), acc);
        int o = s*16 + m; float bias = bfc2[o];
        #pragma unroll
        for (int r = 0; r < 4; ++r)
            Ds[(wave*16 + q*4 + r)*161 + o] += acc[r] + bias;   // wave-private rows: no race
    }
    __syncthreads();
    float* ob = out + (size_t)bb*Cn*HWn + hw0;
    for (int idx = tid; idx < 160*64; idx += 256){
        int o = idx >> 6, p = idx & 63;
        ob[(size_t)o*HWn + p] = Ds[p*161 + o];
    }
}

extern "C" void kernel_launch(void* const* d_in, const int* in_sizes, int n_in,
                              void* d_out, int out_size, void* d_ws, size_t ws_size,
                              hipStream_t stream)
{
    (void)in_sizes; (void)n_in; (void)out_size; (void)ws_size;
    const float* x     = (const float*)d_in[0];
    const float* bn1g  = (const float*)d_in[1];
    const float* bn1b  = (const float*)d_in[2];
    const float* bn1m  = (const float*)d_in[3];
    const float* bn1v  = (const float*)d_in[4];
    const float* wt    = (const float*)d_in[5];
    const float* bt    = (const float*)d_in[6];
    const float* wb    = (const float*)d_in[7];
    const float* bb    = (const float*)d_in[8];
    const float* wr    = (const float*)d_in[9];
    const float* br    = (const float*)d_in[10];
    const float* wl    = (const float*)d_in[11];
    const float* bl    = (const float*)d_in[12];
    const float* wc    = (const float*)d_in[13];
    const float* bc    = (const float*)d_in[14];
    const float* wf1   = (const float*)d_in[15];
    const float* bf1   = (const float*)d_in[16];
    const float* bn2g  = (const float*)d_in[17];
    const float* bn2b  = (const float*)d_in[18];
    const float* bn2m  = (const float*)d_in[19];
    const float* bn2v  = (const float*)d_in[20];
    const float* wph   = (const float*)d_in[21];
    const float* bph   = (const float*)d_in[22];
    const float* wpw   = (const float*)d_in[23];
    const float* bpw   = (const float*)d_in[24];
    const float* wf2   = (const float*)d_in[25];
    const float* lng   = (const float*)d_in[26];
    const float* lnb   = (const float*)d_in[27];
    const float* wfc1  = (const float*)d_in[28];
    const float* bfc1  = (const float*)d_in[29];
    const float* wfc2  = (const float*)d_in[30];
    const float* bfc2v = (const float*)d_in[31];
    float* outp = (float*)d_out;

    // workspace layout (bytes); bf16 [Pn][160] buffer = 32,112,640 B
    const size_t PC2 = (size_t)Pn*160*2;
    char* ws = (char*)d_ws;
    bf16* hT   = (bf16*)(ws + 0*PC2);
    bf16* y5T  = (bf16*)(ws + 1*PC2);
    bf16* gT   = (bf16*)(ws + 2*PC2);
    bf16* xhT  = (bf16*)(ws + 3*PC2);
    bf16* xwT  = (bf16*)(ws + 4*PC2);
    bf16* gm   = (bf16*)(ws + 5*PC2);
    char* wsw  = ws + 6*PC2;                       // weights @ 192,675,840
    bf16*  wcat  = (bf16*)(wsw + 0);
    bf16*  wf1b  = (bf16*)(wsw + 51200);
    bf16*  wf2b  = (bf16*)(wsw + 102400);
    bf16*  wfc1b = (bf16*)(wsw + 256000);
    bf16*  wfc2b = (bf16*)(wsw + 409600);
    bf16*  wphb  = (bf16*)(wsw + 563200);
    bf16*  wpwb  = (bf16*)(wsw + 571392);
    float* bcat  = (float*)(wsw + 579584);
    float* epsv  = (float*)(wsw + 580224);
    float* eptv  = (float*)(wsw + 580864);
    bf16* uB   = (bf16*)(ws + 0);                  // [Pn][480] bf16, reuses hT/y5T/gT (dead by k7)
    // total ws use: 192.7 MB + 0.6 MB = 193.3 MB (< proven 224.8 MB)

    const int GP = Pn/64;     // 1568
    const int GS = Bn*56;     // 1792

    k0_prep<<<1134, 256, 0, stream>>>(wt, wb, wr, wl, wc, bt, bb, br, bl, bc,
                                      wf1, bf1, bn2g, bn2b, bn2m, bn2v,
                                      wf2, wfc1, wfc2, wph, wpw,
                                      wcat, wf1b, wf2b, wfc1b, wfc2b, wphb, wpwb,
                                      bcat, epsv, eptv);
    k1_bn_gelu_tr<<<GP, 256, 0, stream>>>(x, bn1g, bn1b, bn1m, bn1v, hT);
    k2_conv5     <<<GP, 256, 0, stream>>>(hT, wcat, bcat, y5T);
    k3_wf1       <<<GP, 256, 0, stream>>>(y5T, wf1b, epsv, eptv, gT);
    k4_projh     <<<GS, 256, 0, stream>>>(gT, wphb, bph, xhT);
    k5_projw     <<<GS, 256, 0, stream>>>(gT, wpwb, bpw, xwT);
    k6_wf2       <<<GP, 256, 0, stream>>>(gT, xhT, xwT, wf2b, gm);
    k7_ln_fc1    <<<GP, 256, 0, stream>>>(x, gm, lng, lnb, wfc1b, bfc1, uB);
    k8_fc2       <<<GP, 256, 0, stream>>>(uB, wfc2b, bfc2v, x, gm, outp);
}

// Round 5
// 648.969 us; speedup vs baseline: 1.0823x; 1.0823x over previous
//
#include <hip/hip_runtime.h>
#include <hip/hip_bf16.h>
#include <math.h>

typedef __hip_bfloat16 bf16;
typedef unsigned short u16;
typedef __attribute__((ext_vector_type(8))) short s8v;   // 8 bf16 bit-carrier (4 VGPR)
typedef __attribute__((ext_vector_type(4))) float f4v;   // MFMA 16x16 accumulator

#define Bn  32
#define Cn  160
#define HWn 3136
#define Pn  100352

__device__ __forceinline__ float b2f(bf16 v){ return __bfloat162float(v); }
__device__ __forceinline__ bf16  f2b(float v){ return __float2bfloat16(v); }
__device__ __forceinline__ float bits2f(u16 u){
    union { float f; unsigned int i; } x; x.i = ((unsigned int)u) << 16; return x.f;
}
__device__ __forceinline__ u16 f2bits(float v){
    union { u16 us; bf16 b; } cv; cv.b = __float2bfloat16(v); return cv.us;
}
__device__ __forceinline__ float gelu_f(float x){ return 0.5f*x*(1.0f + erff(x*0.7071067811865476f)); }

#define MFMA(a,b,c) __builtin_amdgcn_mfma_f32_16x16x32_bf16((a),(b),(c),0,0,0)

// ---------------- K0: weight prep (fp32 -> bf16, concat/pad) ----------------
__global__ __launch_bounds__(256) void k0_prep(
    const float* __restrict__ wt, const float* __restrict__ wb_, const float* __restrict__ wr,
    const float* __restrict__ wl, const float* __restrict__ wc,
    const float* __restrict__ bt, const float* __restrict__ bb_, const float* __restrict__ br,
    const float* __restrict__ bl, const float* __restrict__ bc,
    const float* __restrict__ wf1, const float* __restrict__ bf1,
    const float* __restrict__ g2, const float* __restrict__ b2, const float* __restrict__ m2, const float* __restrict__ v2,
    const float* __restrict__ wf2, const float* __restrict__ wfc1, const float* __restrict__ wfc2,
    const float* __restrict__ wph, const float* __restrict__ wpw,
    bf16* wcat, bf16* wf1b, bf16* wf2b, bf16* wfc1b, bf16* wfc2b, bf16* wphb, bf16* wpwb,
    float* bcat, float* epsv, float* eptv)
{
    int idx = blockIdx.x*256 + threadIdx.x;
    if (idx < 25600){ int o = idx/160, k = idx - o*160; int gi = o>>5, oo = o&31;
        const float* wp = gi==0?wt: gi==1?wb_: gi==2?wr: gi==3?wl: wc;
        wcat[idx] = f2b(wp[oo*160+k]); return; }
    idx -= 25600;
    if (idx < 25600){ wf1b[idx] = f2b(wf1[idx]); return; }
    idx -= 25600;
    if (idx < 76800){ wf2b[idx] = f2b(wf2[idx]); return; }
    idx -= 76800;
    if (idx < 76800){ wfc1b[idx] = f2b(wfc1[idx]); return; }
    idx -= 76800;
    if (idx < 76800){ wfc2b[idx] = f2b(wfc2[idx]); return; }
    idx -= 76800;
    if (idx < 4096){ int v = idx>>6, w = idx&63;
        wphb[idx] = (v<56 && w<56) ? f2b(wph[v*56+w]) : f2b(0.f); return; }
    idx -= 4096;
    if (idx < 4096){ int v = idx>>6, w = idx&63;
        wpwb[idx] = (v<56 && w<56) ? f2b(wpw[v*56+w]) : f2b(0.f); return; }
    idx -= 4096;
    if (idx < 160){ int o = idx; int gi = o>>5, oo = o&31;
        const float* bp = gi==0?bt: gi==1?bb_: gi==2?br: gi==3?bl: bc;
        bcat[o] = bp[oo]; return; }
    idx -= 160;
    if (idx < 160){ int o = idx; float s = g2[o]*rsqrtf(v2[o]+1e-5f);
        epsv[o] = s; eptv[o] = (bf1[o]-m2[o])*s + b2[o]; return; }
}

// ---------------- K12: fused bn1+gelu+conv5. 128 pos/block, B in LDS. ----------------
__global__ __launch_bounds__(256,2) void k12_conv5(const float* __restrict__ x,
    const float* __restrict__ g, const float* __restrict__ b,
    const float* __restrict__ mm, const float* __restrict__ vv,
    const bf16* __restrict__ wcat, const float* __restrict__ bcat, bf16* __restrict__ y5T)
{
    __shared__ __align__(16) u16 Bs[160*168];
    __shared__ float sc[160], sh[160];
    int tid = threadIdx.x, w = tid>>6, lane = tid&63, m = lane&15, q = lane>>4;
    size_t pos0 = (size_t)blockIdx.x*128;
    // stage B (full 160x160) + bn tables
    { const s8v* sp = (const s8v*)wcat;
      for (int c = tid; c < 3200; c += 256){ int row = c/20, col = (c - row*20)*8;
          *(s8v*)&Bs[row*168 + col] = sp[c]; } }
    if (tid < 160){
        float s = g[tid] * rsqrtf(vv[tid] + 1e-5f);
        sc[tid] = s; sh[tid] = b[tid] - mm[tid]*s;
    }
    __syncthreads();
    // build A fragments in registers: bn1+gelu on the fly
    s8v a[2][5];
    #pragma unroll
    for (int mf = 0; mf < 2; ++mf){
        int pos = (int)pos0 + w*32 + mf*16 + m;
        int bb = pos/HWn, hw = pos - bb*HWn;
        const float* base = x + (size_t)bb*Cn*HWn + hw;
        #pragma unroll
        for (int kb = 0; kb < 5; ++kb){
            s8v av;
            #pragma unroll
            for (int j = 0; j < 8; ++j){
                int c = kb*32 + q*8 + j;
                float val = base[(size_t)c*HWn];
                val = gelu_f(val*sc[c] + sh[c]);
                av[j] = (short)f2bits(val);
            }
            a[mf][kb] = av;
        }
    }
    for (int s = 0; s < 10; ++s){
        s8v bf[5];
        const u16* Bp = &Bs[(s*16+m)*168 + q*8];
        #pragma unroll
        for (int kb = 0; kb < 5; ++kb) bf[kb] = *(const s8v*)(Bp + kb*32);
        f4v acc0 = {0,0,0,0}, acc1 = {0,0,0,0};
        #pragma unroll
        for (int kb = 0; kb < 5; ++kb){
            acc0 = MFMA(a[0][kb], bf[kb], acc0);
            acc1 = MFMA(a[1][kb], bf[kb], acc1);
        }
        float bias = bcat[s*16 + m];
        bf16* yo0 = y5T + (pos0 + w*32 + q*4)*160 + s*16 + m;
        bf16* yo1 = yo0 + 16*160;
        #pragma unroll
        for (int r = 0; r < 4; ++r){
            yo0[r*160] = f2b(acc0[r] + bias);
            yo1[r*160] = f2b(acc1[r] + bias);
        }
    }
}

// ---------------- K3: shifted-A GEMM + bn2 + gelu -> gT. 128 pos/block, B in LDS. ----------------
__global__ __launch_bounds__(256,2) void k3_wf1(const bf16* __restrict__ y5T,
    const bf16* __restrict__ wf1b, const float* __restrict__ epsv, const float* __restrict__ eptv,
    bf16* __restrict__ gT)
{
    __shared__ __align__(16) u16 Bs[160*168];
    int tid = threadIdx.x, w = tid>>6, lane = tid&63, m = lane&15, q = lane>>4;
    size_t pos0 = (size_t)blockIdx.x*128;
    { const s8v* sp = (const s8v*)wf1b;
      for (int c = tid; c < 3200; c += 256){ int row = c/20, col = (c - row*20)*8;
          *(s8v*)&Bs[row*168 + col] = sp[c]; } }
    s8v a[2][5];
    #pragma unroll
    for (int mf = 0; mf < 2; ++mf){
        int pos = (int)pos0 + w*32 + mf*16 + m;
        int bb = pos/HWn, hw = pos - bb*HWn;
        int h = hw/56, ww = hw - h*56;
        #pragma unroll
        for (int kb = 0; kb < 5; ++kb){
            int h2 = h, w2 = ww; bool ok = true;
            if      (kb == 0){ h2 = h+1; ok = (h2 < 56); }
            else if (kb == 1){ h2 = h-1; ok = (h2 >= 0); }
            else if (kb == 2){ w2 = ww-1; ok = (w2 >= 0); }
            else if (kb == 3){ w2 = ww+1; ok = (w2 < 56); }
            if (ok)
                a[mf][kb] = *(const s8v*)((const u16*)y5T + ((size_t)bb*HWn + h2*56 + w2)*160 + kb*32 + q*8);
            else
                a[mf][kb] = (s8v){0,0,0,0,0,0,0,0};
        }
    }
    __syncthreads();
    for (int s = 0; s < 10; ++s){
        s8v bf[5];
        const u16* Bp = &Bs[(s*16+m)*168 + q*8];
        #pragma unroll
        for (int kb = 0; kb < 5; ++kb) bf[kb] = *(const s8v*)(Bp + kb*32);
        f4v acc0 = {0,0,0,0}, acc1 = {0,0,0,0};
        #pragma unroll
        for (int kb = 0; kb < 5; ++kb){
            acc0 = MFMA(a[0][kb], bf[kb], acc0);
            acc1 = MFMA(a[1][kb], bf[kb], acc1);
        }
        int o = s*16 + m;
        float es = epsv[o], et = eptv[o];
        bf16* go0 = gT + (pos0 + w*32 + q*4)*160 + o;
        bf16* go1 = go0 + 16*160;
        #pragma unroll
        for (int r = 0; r < 4; ++r){
            go0[r*160] = f2b(gelu_f(acc0[r]*es + et));
            go1[r*160] = f2b(gelu_f(acc1[r]*es + et));
        }
    }
}

// ---------------- K4: proj_h MFMA ----------------
__global__ __launch_bounds__(256) void k4_projh(const bf16* __restrict__ gT,
    const bf16* __restrict__ wphb, const float* __restrict__ bph, bf16* __restrict__ xhT)
{
    __shared__ __align__(16) u16 gS[160*72];
    int tid = threadIdx.x, wave = tid>>6, lane = tid&63, m = lane&15, q = lane>>4;
    int blk = blockIdx.x; int b = blk/56, h = blk - b*56;
    const u16* ga = (const u16*)gT + ((size_t)b*HWn + h*56)*160;
    for (int idx = tid; idx < 56*160; idx += 256){
        int w = idx/160, c = idx - w*160;
        gS[c*72 + w] = ga[idx];
    }
    for (int idx = tid; idx < 160*8; idx += 256){
        int c = idx>>3, w = 56 + (idx&7);
        gS[c*72 + w] = 0;
    }
    __syncthreads();
    int v0 = wave*16;
    s8v a[2];
    #pragma unroll
    for (int kb = 0; kb < 2; ++kb)
        a[kb] = *(const s8v*)((const u16*)wphb + (v0+m)*64 + kb*32 + q*8);
    int v = v0 + q*4;
    for (int s = 0; s < 10; ++s){
        f4v acc = {0,0,0,0};
        const u16* Bp = &gS[(s*16+m)*72 + q*8];
        #pragma unroll
        for (int kb = 0; kb < 2; ++kb) acc = MFMA(a[kb], *(const s8v*)(Bp + kb*32), acc);
        #pragma unroll
        for (int r = 0; r < 4; ++r){
            int vvv = v + r;
            if (vvv < 56)
                xhT[((size_t)b*HWn + h*56 + vvv)*160 + s*16 + m] = f2b(acc[r] + bph[vvv]);
        }
    }
}

// ---------------- K5: proj_w MFMA ----------------
__global__ __launch_bounds__(256) void k5_projw(const bf16* __restrict__ gT,
    const bf16* __restrict__ wpwb, const float* __restrict__ bpw, bf16* __restrict__ xwT)
{
    __shared__ __align__(16) u16 gS[160*72];
    int tid = threadIdx.x, wave = tid>>6, lane = tid&63, m = lane&15, q = lane>>4;
    int blk = blockIdx.x; int b = blk/56, w = blk - b*56;
    const u16* gbase = (const u16*)gT + ((size_t)b*HWn + w)*160;
    for (int idx = tid; idx < 56*160; idx += 256){
        int hh = idx/160, c = idx - hh*160;
        gS[c*72 + hh] = gbase[(size_t)hh*56*160 + c];
    }
    for (int idx = tid; idx < 160*8; idx += 256){
        int c = idx>>3, hh = 56 + (idx&7);
        gS[c*72 + hh] = 0;
    }
    __syncthreads();
    int v0 = wave*16;
    s8v a[2];
    #pragma unroll
    for (int kb = 0; kb < 2; ++kb)
        a[kb] = *(const s8v*)((const u16*)wpwb + (v0+m)*64 + kb*32 + q*8);
    int v = v0 + q*4;
    for (int s = 0; s < 10; ++s){
        f4v acc = {0,0,0,0};
        const u16* Bp = &gS[(s*16+m)*72 + q*8];
        #pragma unroll
        for (int kb = 0; kb < 2; ++kb) acc = MFMA(a[kb], *(const s8v*)(Bp + kb*32), acc);
        #pragma unroll
        for (int r = 0; r < 4; ++r){
            int vvv = v + r;
            if (vvv < 56)
                xwT[((size_t)b*HWn + vvv*56 + w)*160 + s*16 + m] = f2b(acc[r] + bpw[vvv]);
        }
    }
}

// ---------------- K6: wf2 GEMM (K=480, 3 LDS-staged k-chunks) -> gm bf16 BHWC -------------
__global__ __launch_bounds__(256,2) void k6_wf2(const bf16* __restrict__ gT,
    const bf16* __restrict__ xhT, const bf16* __restrict__ xwT,
    const bf16* __restrict__ wf2b, bf16* __restrict__ gm)
{
    __shared__ __align__(16) u16 Bs[160*168];
    int tid = threadIdx.x, w = tid>>6, lane = tid&63, m = lane&15, q = lane>>4;
    size_t pos0 = (size_t)blockIdx.x*128;
    f4v acc[10][2];
    #pragma unroll
    for (int s = 0; s < 10; ++s){ acc[s][0] = (f4v){0,0,0,0}; acc[s][1] = (f4v){0,0,0,0}; }
    for (int kc = 0; kc < 3; ++kc){
        __syncthreads();
        { const u16* wsrc = (const u16*)wf2b + kc*160;
          for (int c = tid; c < 3200; c += 256){ int row = c/20, col = (c - row*20)*8;
              *(s8v*)&Bs[row*168 + col] = *(const s8v*)(wsrc + row*480 + col); } }
        const bf16* src = (kc==0) ? gT : (kc==1 ? xhT : xwT);
        s8v a[2][5];
        #pragma unroll
        for (int mf = 0; mf < 2; ++mf){
            const u16* Ap = (const u16*)src + (pos0 + w*32 + mf*16 + m)*160 + q*8;
            #pragma unroll
            for (int kb = 0; kb < 5; ++kb) a[mf][kb] = *(const s8v*)(Ap + kb*32);
        }
        __syncthreads();
        for (int s = 0; s < 10; ++s){
            s8v bf[5];
            const u16* Bp = &Bs[(s*16+m)*168 + q*8];
            #pragma unroll
            for (int kb = 0; kb < 5; ++kb) bf[kb] = *(const s8v*)(Bp + kb*32);
            #pragma unroll
            for (int kb = 0; kb < 5; ++kb){
                acc[s][0] = MFMA(a[0][kb], bf[kb], acc[s][0]);
                acc[s][1] = MFMA(a[1][kb], bf[kb], acc[s][1]);
            }
        }
    }
    for (int s = 0; s < 10; ++s){
        bf16* go0 = gm + (pos0 + w*32 + q*4)*160 + s*16 + m;
        bf16* go1 = go0 + 16*160;
        #pragma unroll
        for (int r = 0; r < 4; ++r){
            go0[r*160] = f2b(acc[s][0][r]);
            go1[r*160] = f2b(acc[s][1][r]);
        }
    }
}

// ---------------- KMLP: fused  x+gm -> LN -> fc1 -> gelu -> fc2 -> +res -> out ----------------
__global__ __launch_bounds__(256,1) void kmlp(const float* __restrict__ x,
    const bf16* __restrict__ gm,
    const float* __restrict__ lng, const float* __restrict__ lnb,
    const bf16* __restrict__ wfc1b, const float* __restrict__ bfc1,
    const bf16* __restrict__ wfc2b, const float* __restrict__ bfc2,
    float* __restrict__ out)
{
    __shared__ float Xs[64*161];                 // x+gm (kept for residual), 41216 B
    __shared__ __align__(16) u16 As[64*168];     // LN'd activations, 21504 B
    __shared__ __align__(16) u16 Us[64*488];     // fc1 output u, 62464 B
    int tid = threadIdx.x, w = tid>>6, lane = tid&63, m = lane&15, q = lane>>4;
    int blk = blockIdx.x; int bb = blk/49; int hw0 = (blk - bb*49)*64;
    size_t pos0 = (size_t)bb*HWn + hw0;
    // phase 1: Xs = x (transposed) + gm
    const float* xb = x + (size_t)bb*Cn*HWn + hw0;
    for (int idx = tid; idx < 160*64; idx += 256){
        int o = idx >> 6, p = idx & 63;
        Xs[p*161 + o] = xb[(size_t)o*HWn + p];
    }
    __syncthreads();
    { const u16* gp = (const u16*)gm + pos0*160;
      for (int idx = tid; idx < 64*160; idx += 256){
          int p = idx/160, c = idx - p*160;
          Xs[p*161 + c] += bits2f(gp[idx]);
      } }
    __syncthreads();
    // phase 2: LN per position -> As (bf16)
    {
        int p = tid >> 2, q4 = tid & 3;
        float vbuf[40];
        float s = 0.f, ss = 0.f;
        const float* row = &Xs[p*161 + q4*40];
        #pragma unroll
        for (int i = 0; i < 40; ++i){ float v = row[i]; vbuf[i] = v; s += v; ss += v*v; }
        s  += __shfl_xor(s, 1);  ss += __shfl_xor(ss, 1);
        s  += __shfl_xor(s, 2);  ss += __shfl_xor(ss, 2);
        float mean = s * (1.f/160.f);
        float var  = ss * (1.f/160.f) - mean*mean;
        float rstd = rsqrtf(var + 1e-5f);
        u16* arow = &As[p*168 + q4*40];
        #pragma unroll
        for (int i = 0; i < 40; ++i){
            int c = q4*40 + i;
            arow[i] = f2bits((vbuf[i] - mean)*rstd*lng[c] + lnb[c]);
        }
    }
    __syncthreads();
    // phase 3: fc1 (wave owns 16 positions = m-frag w; all 30 out-strips)
    {
        s8v a[5];
        const u16* Ap = &As[(w*16 + m)*168 + q*8];
        #pragma unroll
        for (int kb = 0; kb < 5; ++kb) a[kb] = *(const s8v*)(Ap + kb*32);
        const u16* wb = (const u16*)wfc1b + m*160 + q*8;
        s8v B0[5], B1[5];
        #pragma unroll
        for (int kb = 0; kb < 5; ++kb) B0[kb] = *(const s8v*)(wb + kb*32);
        for (int s = 0; s < 30; ++s){
            if (s+1 < 30){
                const u16* nb = wb + (size_t)(s+1)*2560;
                #pragma unroll
                for (int kb = 0; kb < 5; ++kb) B1[kb] = *(const s8v*)(nb + kb*32);
            }
            f4v acc = {0,0,0,0};
            #pragma unroll
            for (int kb = 0; kb < 5; ++kb) acc = MFMA(a[kb], B0[kb], acc);
            float bias = bfc1[s*16 + m];
            u16* uo = &Us[(w*16 + q*4)*488 + s*16 + m];
            #pragma unroll
            for (int r = 0; r < 4; ++r) uo[r*488] = f2bits(gelu_f(acc[r] + bias));
            #pragma unroll
            for (int kb = 0; kb < 5; ++kb) B0[kb] = B1[kb];
        }
    }
    __syncthreads();
    // phase 4: fc2 (wave owns m-frag w; all 10 out-strips), accumulate into Xs
    {
        s8v a[15];
        const u16* Ap = &Us[(w*16 + m)*488 + q*8];
        #pragma unroll
        for (int kb = 0; kb < 15; ++kb) a[kb] = *(const s8v*)(Ap + kb*32);
        const u16* wb = (const u16*)wfc2b + m*480 + q*8;
        s8v B0[15], B1[15];
        #pragma unroll
        for (int kb = 0; kb < 15; ++kb) B0[kb] = *(const s8v*)(wb + kb*32);
        for (int s = 0; s < 10; ++s){
            if (s+1 < 10){
                const u16* nb = wb + (size_t)(s+1)*7680;
                #pragma unroll
                for (int kb = 0; kb < 15; ++kb) B1[kb] = *(const s8v*)(nb + kb*32);
            }
            f4v acc = {0,0,0,0};
            #pragma unroll
            for (int kb = 0; kb < 15; ++kb) acc = MFMA(a[kb], B0[kb], acc);
            int o = s*16 + m; float bias = bfc2[o];
            #pragma unroll
            for (int r = 0; r < 4; ++r)
                Xs[(w*16 + q*4 + r)*161 + o] += acc[r] + bias;   // wave-private rows
            #pragma unroll
            for (int kb = 0; kb < 15; ++kb) B0[kb] = B1[kb];
        }
    }
    __syncthreads();
    // phase 5: write out NCHW fp32
    float* ob = out + (size_t)bb*Cn*HWn + hw0;
    for (int idx = tid; idx < 160*64; idx += 256){
        int o = idx >> 6, p = idx & 63;
        ob[(size_t)o*HWn + p] = Xs[p*161 + o];
    }
}

extern "C" void kernel_launch(void* const* d_in, const int* in_sizes, int n_in,
                              void* d_out, int out_size, void* d_ws, size_t ws_size,
                              hipStream_t stream)
{
    (void)in_sizes; (void)n_in; (void)out_size; (void)ws_size;
    const float* x     = (const float*)d_in[0];
    const float* bn1g  = (const float*)d_in[1];
    const float* bn1b  = (const float*)d_in[2];
    const float* bn1m  = (const float*)d_in[3];
    const float* bn1v  = (const float*)d_in[4];
    const float* wt    = (const float*)d_in[5];
    const float* bt    = (const float*)d_in[6];
    const float* wb    = (const float*)d_in[7];
    const float* bb    = (const float*)d_in[8];
    const float* wr    = (const float*)d_in[9];
    const float* br    = (const float*)d_in[10];
    const float* wl    = (const float*)d_in[11];
    const float* bl    = (const float*)d_in[12];
    const float* wc    = (const float*)d_in[13];
    const float* bc    = (const float*)d_in[14];
    const float* wf1   = (const float*)d_in[15];
    const float* bf1   = (const float*)d_in[16];
    const float* bn2g  = (const float*)d_in[17];
    const float* bn2b  = (const float*)d_in[18];
    const float* bn2m  = (const float*)d_in[19];
    const float* bn2v  = (const float*)d_in[20];
    const float* wph   = (const float*)d_in[21];
    const float* bph   = (const float*)d_in[22];
    const float* wpw   = (const float*)d_in[23];
    const float* bpw   = (const float*)d_in[24];
    const float* wf2   = (const float*)d_in[25];
    const float* lng   = (const float*)d_in[26];
    const float* lnb   = (const float*)d_in[27];
    const float* wfc1  = (const float*)d_in[28];
    const float* bfc1  = (const float*)d_in[29];
    const float* wfc2  = (const float*)d_in[30];
    const float* bfc2v = (const float*)d_in[31];
    float* outp = (float*)d_out;

    const size_t PC2 = (size_t)Pn*160*2;      // 32,112,640 B per bf16 [Pn][160] buffer
    char* ws = (char*)d_ws;
    bf16* y5T  = (bf16*)(ws + 1*PC2);
    bf16* gT   = (bf16*)(ws + 2*PC2);
    bf16* xhT  = (bf16*)(ws + 3*PC2);
    bf16* xwT  = (bf16*)(ws + 4*PC2);
    bf16* gm   = (bf16*)(ws + 5*PC2);
    char* wsw  = ws + 6*PC2;                  // weights @ 192,675,840
    bf16*  wcat  = (bf16*)(wsw + 0);
    bf16*  wf1b  = (bf16*)(wsw + 51200);
    bf16*  wf2b  = (bf16*)(wsw + 102400);
    bf16*  wfc1b = (bf16*)(wsw + 256000);
    bf16*  wfc2b = (bf16*)(wsw + 409600);
    bf16*  wphb  = (bf16*)(wsw + 563200);
    bf16*  wpwb  = (bf16*)(wsw + 571392);
    float* bcat  = (float*)(wsw + 579584);
    float* epsv  = (float*)(wsw + 580224);
    float* eptv  = (float*)(wsw + 580864);
    // total ws use: 193.3 MB (< proven 224.8 MB)

    const int GP128 = Pn/128;   // 784
    const int GP64  = Pn/64;    // 1568
    const int GS    = Bn*56;    // 1792

    k0_prep<<<1134, 256, 0, stream>>>(wt, wb, wr, wl, wc, bt, bb, br, bl, bc,
                                      wf1, bf1, bn2g, bn2b, bn2m, bn2v,
                                      wf2, wfc1, wfc2, wph, wpw,
                                      wcat, wf1b, wf2b, wfc1b, wfc2b, wphb, wpwb,
                                      bcat, epsv, eptv);
    k12_conv5<<<GP128, 256, 0, stream>>>(x, bn1g, bn1b, bn1m, bn1v, wcat, bcat, y5T);
    k3_wf1   <<<GP128, 256, 0, stream>>>(y5T, wf1b, epsv, eptv, gT);
    k4_projh <<<GS,    256, 0, stream>>>(gT, wphb, bph, xhT);
    k5_projw <<<GS,    256, 0, stream>>>(gT, wpwb, bpw, xwT);
    k6_wf2   <<<GP128, 256, 0, stream>>>(gT, xhT, xwT, wf2b, gm);
    kmlp     <<<GP64,  256, 0, stream>>>(x, gm, lng, lnb, wfc1b, bfc1, wfc2b, bfc2v, outp);
}